// Round 1
// 1022.920 us; speedup vs baseline: 1.1772x; 1.1772x over previous
//
#include <hip/hip_runtime.h>

#define BB 16
#define NV 1024
#define NH 1024
#define DD 1024

typedef _Float16 f16x8 __attribute__((ext_vector_type(8)));
typedef _Float16 f16x4 __attribute__((ext_vector_type(4)));
typedef float f32x4 __attribute__((ext_vector_type(4)));

// ---------------- cast fp32 -> fp16 ----------------
__global__ __launch_bounds__(256) void cast_k(const float* __restrict__ in,
                                              _Float16* __restrict__ out, long n4) {
  long i = (long)blockIdx.x * 256 + threadIdx.x;
  long stride = (long)gridDim.x * 256;
  for (; i < n4; i += stride) {
    float4 x = ((const float4*)in)[i];
    f16x4 o;
    o[0] = (_Float16)x.x; o[1] = (_Float16)x.y;
    o[2] = (_Float16)x.z; o[3] = (_Float16)x.w;
    ((f16x4*)out)[i] = o;
  }
}

// ---------------- split fp32 -> (hi, lo) fp16 pair ----------------
__global__ __launch_bounds__(256) void split_k(const float* __restrict__ in,
                                               _Float16* __restrict__ hi,
                                               _Float16* __restrict__ lo, long n4) {
  long i = (long)blockIdx.x * 256 + threadIdx.x;
  long stride = (long)gridDim.x * 256;
  for (; i < n4; i += stride) {
    float4 x = ((const float4*)in)[i];
    f16x4 h, l;
    h[0] = (_Float16)x.x; h[1] = (_Float16)x.y;
    h[2] = (_Float16)x.z; h[3] = (_Float16)x.w;
    l[0] = (_Float16)(x.x - (float)h[0]);
    l[1] = (_Float16)(x.y - (float)h[1]);
    l[2] = (_Float16)(x.z - (float)h[2]);
    l[3] = (_Float16)(x.w - (float)h[3]);
    ((f16x4*)hi)[i] = h;
    ((f16x4*)lo)[i] = l;
  }
}

// ---------------- async global->LDS (16B/lane) ----------------
__device__ inline void gl_lds16(const _Float16* g, _Float16* l) {
  __builtin_amdgcn_global_load_lds((__attribute__((address_space(1))) void*)g,
                                   (__attribute__((address_space(3))) void*)l,
                                   16, 0, 0);
}

// XCD-aware decode for 256-block grids (1 block/CU), N fixed = 1024 (4 bn tiles of 256).
// NB==1:  M=16384 (64 bm tiles): each XCD gets a contiguous band of 8 bm x 4 bn.
// NB==16: per-batch 1024x1024 (4 bm x 4 bn): each XCD gets 2 whole batches.
__device__ inline void decode256(int flat, int NB, int& bm, int& bn, int& bz) {
  int xcd = flat & 7, j = flat >> 3;  // j in [0,32)
  if (NB == 1) {
    bz = 0;
    bm = xcd * 8 + (j >> 2);
    bn = j & 3;
  } else {
    bz = xcd * 2 + (j >> 4);
    int r = j & 15;
    bm = r >> 2;
    bn = r & 3;
  }
}

// ---------------- 256x256-tile single-precision NT GEMM, 8 waves, 4-deep LDS ring
// C[M,1024] = A[M,K] * B[1024,K]^T (+bias). Counted-vmcnt pipeline, 1 barrier/K-tile.
template <typename CT>
__global__ __launch_bounds__(512) void gemm256_nt_k(
    const _Float16* __restrict__ A, const _Float16* __restrict__ B,
    CT* __restrict__ C, const float* __restrict__ bias,
    int K, int NB, long sA, long sB, long sC) {
  __shared__ _Float16 lds[65536];  // 4 bufs x (A 8192 + B 8192) halfwords = 128 KB
  const int tid = threadIdx.x;
  const int w = tid >> 6, l = tid & 63;
  int bm, bn, bz;
  decode256(blockIdx.x, NB, bm, bn, bz);
  const _Float16* Ab = A + (long)bz * sA;
  const _Float16* Bb = B + (long)bz * sB;
  CT* Cb = C + (long)bz * sC;

  // staging: per round r (0,1): row = r*128 + w*16 + (l>>2), 16B slot = l&3
  const int srow = w * 16 + (l >> 2);
  const int sslot = l & 3;
  const _Float16* gA = Ab + (long)(bm * 256 + srow) * K + sslot * 8;
  const _Float16* gB = Bb + (long)(bn * 256 + srow) * K + sslot * 8;
  const long rs128 = (long)128 * K;
  const int T = K >> 5;

  // fragment addressing (identical mapping to the verified 128^2 kernel)
  const int fr = l & 15, fq = l >> 4;
  const int wm = w >> 2, wn = w & 3;
  const int aoff = (wm * 128 + fr) * 32 + fq * 8;  // + m*512
  const int boff = (wn * 64 + fr) * 32 + fq * 8;   // + n*512

  f32x4 acc[8][4] = {};

  auto stage = [&](int st) {
    _Float16* dA = lds + (st & 3) * 16384 + w * 512;
    _Float16* dB = dA + 8192;
    const _Float16* pA = gA + st * 32;
    const _Float16* pB = gB + st * 32;
    gl_lds16(pA, dA);
    gl_lds16(pA + rs128, dA + 4096);
    gl_lds16(pB, dB);
    gl_lds16(pB + rs128, dB + 4096);
  };

  // prologue: 3 tiles in flight; wait for tile 0 (2 newest tiles may stay outstanding)
  stage(0); stage(1); stage(2);
  asm volatile("s_waitcnt vmcnt(8)" ::: "memory");
  __builtin_amdgcn_s_barrier();
  __builtin_amdgcn_sched_barrier(0);

  for (int t = 0; t < T; ++t) {
    const _Float16* bufA = lds + (t & 3) * 16384;
    const _Float16* bufB = bufA + 8192;
    if (t + 3 < T) stage(t + 3);  // targets buf (t+3)&3 == (t-1)&3: reads done before
                                  // the barrier that ended tile t-1 -> safe.
    f16x8 bf[4], af[4];
#pragma unroll
    for (int n = 0; n < 4; ++n) bf[n] = *(const f16x8*)&bufB[boff + n * 512];
#pragma unroll
    for (int m = 0; m < 4; ++m) af[m] = *(const f16x8*)&bufA[aoff + m * 512];
    __builtin_amdgcn_s_setprio(1);
#pragma unroll
    for (int m = 0; m < 4; ++m)
#pragma unroll
      for (int n = 0; n < 4; ++n)
        acc[m][n] = __builtin_amdgcn_mfma_f32_16x16x32_f16(af[m], bf[n], acc[m][n], 0, 0, 0);
    __builtin_amdgcn_s_setprio(0);
#pragma unroll
    for (int m = 0; m < 4; ++m) af[m] = *(const f16x8*)&bufA[aoff + (m + 4) * 512];
    __builtin_amdgcn_s_setprio(1);
#pragma unroll
    for (int m = 0; m < 4; ++m)
#pragma unroll
      for (int n = 0; n < 4; ++n)
        acc[m + 4][n] = __builtin_amdgcn_mfma_f32_16x16x32_f16(af[m], bf[n], acc[m + 4][n], 0, 0, 0);
    __builtin_amdgcn_s_setprio(0);
    if (t + 1 < T) {
      // need tile t+1 landed; tiles t+2, t+3 (4 loads each) may stay in flight
      const int hi = (t + 3 < T) ? t + 3 : T - 1;
      const int cnt = 4 * (hi - (t + 1));
      if (cnt >= 8)      asm volatile("s_waitcnt vmcnt(8)" ::: "memory");
      else if (cnt == 4) asm volatile("s_waitcnt vmcnt(4)" ::: "memory");
      else               asm volatile("s_waitcnt vmcnt(0)" ::: "memory");
      __builtin_amdgcn_s_barrier();
      __builtin_amdgcn_sched_barrier(0);
    }
  }

#pragma unroll
  for (int m = 0; m < 8; ++m) {
    const int grow = bm * 256 + wm * 128 + m * 16 + fq * 4;
#pragma unroll
    for (int n = 0; n < 4; ++n) {
      const int gcol = bn * 256 + wn * 64 + n * 16 + fr;
      const float bv = bias ? bias[gcol] : 0.0f;
#pragma unroll
      for (int e = 0; e < 4; ++e)
        Cb[(long)(grow + e) * 1024 + gcol] = (CT)(acc[m][n][e] + bv);
    }
  }
}

// ---------------- 256x256-tile fused 3-term split GEMM, 8 waves, double-buffered
// C = Ahi*Bhi^T + Alo*Bhi^T + Ahi*Blo^T (+bias) ; optional row-mask -> -30000
// SPLIT_OUT: write (Chi, Clo) fp16 pair; else write Cf fp32.
template <bool SPLIT_OUT>
__global__ __launch_bounds__(512) void gemm3_256_k(
    const _Float16* __restrict__ Ahi, const _Float16* __restrict__ Alo,
    const _Float16* __restrict__ Bhi, const _Float16* __restrict__ Blo,
    float* __restrict__ Cf, _Float16* __restrict__ Chi, _Float16* __restrict__ Clo,
    const float* __restrict__ bias, const int* __restrict__ mask,
    int K, int NB, long sA, long sB, long sC) {
  __shared__ _Float16 lds[65536];  // 2 bufs x (Ah,Al,Bh,Bl x 8192 hw) = 128 KB
  const int tid = threadIdx.x;
  const int w = tid >> 6, l = tid & 63;
  int bm, bn, bz;
  decode256(blockIdx.x, NB, bm, bn, bz);

  const int srow = w * 16 + (l >> 2);
  const int sslot = l & 3;
  const long abase = (long)(bm * 256 + srow) * K + sslot * 8 + (long)bz * sA;
  const long bbase = (long)(bn * 256 + srow) * K + sslot * 8 + (long)bz * sB;
  const _Float16* gAh = Ahi + abase;
  const _Float16* gAl = Alo + abase;
  const _Float16* gBh = Bhi + bbase;
  const _Float16* gBl = Blo + bbase;
  const long rs128 = (long)128 * K;
  const int T = K >> 5;

  const int fr = l & 15, fq = l >> 4;
  const int wm = w >> 2, wn = w & 3;
  const int aoff = (wm * 128 + fr) * 32 + fq * 8;
  const int boff = (wn * 64 + fr) * 32 + fq * 8;

  f32x4 acc[8][4] = {};

  auto stage = [&](int st) {
    _Float16* d = lds + (st & 1) * 32768 + w * 512;
    const int ko = st * 32;
    gl_lds16(gAh + ko, d);
    gl_lds16(gAh + ko + rs128, d + 4096);
    gl_lds16(gAl + ko, d + 8192);
    gl_lds16(gAl + ko + rs128, d + 12288);
    gl_lds16(gBh + ko, d + 16384);
    gl_lds16(gBh + ko + rs128, d + 20480);
    gl_lds16(gBl + ko, d + 24576);
    gl_lds16(gBl + ko + rs128, d + 28672);
  };

  stage(0); stage(1);
  asm volatile("s_waitcnt vmcnt(8)" ::: "memory");  // tile 0 landed; tile 1 in flight
  __builtin_amdgcn_s_barrier();
  __builtin_amdgcn_sched_barrier(0);

  for (int t = 0; t < T; ++t) {
    const _Float16* bA = lds + (t & 1) * 32768;
    const _Float16* bB = bA + 16384;
    f16x8 bh[4], bl[4], ah[4], al[4];
#pragma unroll
    for (int n = 0; n < 4; ++n) {
      bh[n] = *(const f16x8*)&bB[boff + n * 512];
      bl[n] = *(const f16x8*)&bB[8192 + boff + n * 512];
    }
#pragma unroll
    for (int m = 0; m < 4; ++m) {
      ah[m] = *(const f16x8*)&bA[aoff + m * 512];
      al[m] = *(const f16x8*)&bA[8192 + aoff + m * 512];
    }
    __builtin_amdgcn_s_setprio(1);
#pragma unroll
    for (int m = 0; m < 4; ++m)
#pragma unroll
      for (int n = 0; n < 4; ++n) {
        acc[m][n] = __builtin_amdgcn_mfma_f32_16x16x32_f16(ah[m], bh[n], acc[m][n], 0, 0, 0);
        acc[m][n] = __builtin_amdgcn_mfma_f32_16x16x32_f16(al[m], bh[n], acc[m][n], 0, 0, 0);
        acc[m][n] = __builtin_amdgcn_mfma_f32_16x16x32_f16(ah[m], bl[n], acc[m][n], 0, 0, 0);
      }
    __builtin_amdgcn_s_setprio(0);
    // phase-1 A reads: must be data-complete before staging overwrites this buffer
#pragma unroll
    for (int m = 0; m < 4; ++m) {
      ah[m] = *(const f16x8*)&bA[aoff + (m + 4) * 512];
      al[m] = *(const f16x8*)&bA[8192 + aoff + (m + 4) * 512];
    }
    asm volatile("s_waitcnt lgkmcnt(0)" ::: "memory");
    __builtin_amdgcn_s_barrier();            // all waves done reading buf t&1
    __builtin_amdgcn_sched_barrier(0);
    if (t + 2 < T) stage(t + 2);             // reuses buf t&1, now safe
    __builtin_amdgcn_s_setprio(1);
#pragma unroll
    for (int m = 0; m < 4; ++m)
#pragma unroll
      for (int n = 0; n < 4; ++n) {
        acc[m + 4][n] = __builtin_amdgcn_mfma_f32_16x16x32_f16(ah[m], bh[n], acc[m + 4][n], 0, 0, 0);
        acc[m + 4][n] = __builtin_amdgcn_mfma_f32_16x16x32_f16(al[m], bh[n], acc[m + 4][n], 0, 0, 0);
        acc[m + 4][n] = __builtin_amdgcn_mfma_f32_16x16x32_f16(ah[m], bl[n], acc[m + 4][n], 0, 0, 0);
      }
    __builtin_amdgcn_s_setprio(0);
    if (t + 1 < T) {
      if (t + 2 < T) asm volatile("s_waitcnt vmcnt(8)" ::: "memory");  // t+1 landed, t+2 in flight
      else           asm volatile("s_waitcnt vmcnt(0)" ::: "memory");
      __builtin_amdgcn_s_barrier();
      __builtin_amdgcn_sched_barrier(0);
    }
  }

#pragma unroll
  for (int m = 0; m < 8; ++m) {
    const int grow = bm * 256 + wm * 128 + m * 16 + fq * 4;
#pragma unroll
    for (int n = 0; n < 4; ++n) {
      const int gcol = bn * 256 + wn * 64 + n * 16 + fr;
      const float bv = bias ? bias[gcol] : 0.0f;
#pragma unroll
      for (int e = 0; e < 4; ++e) {
        float val = acc[m][n][e] + bv;
        if (mask && mask[grow + e] == 0) val = -30000.0f;
        const long idx = (long)(grow + e) * 1024 + gcol + (long)bz * sC;
        if (SPLIT_OUT) {
          _Float16 hi = (_Float16)val;
          Chi[idx] = hi;
          Clo[idx] = (_Float16)(val - (float)hi);
        } else {
          Cf[idx] = val;
        }
      }
    }
  }
}

// ---------------- wave/block reduce helpers ----------------
__device__ inline float wave_max(float v) {
#pragma unroll
  for (int o = 32; o > 0; o >>= 1) v = fmaxf(v, __shfl_xor(v, o, 64));
  return v;
}
__device__ inline float wave_sum(float v) {
#pragma unroll
  for (int o = 32; o > 0; o >>= 1) v += __shfl_xor(v, o, 64);
  return v;
}

// ---------------- row softmax: att fp32 [rows,1024] -> P fp16 ----------------
__global__ __launch_bounds__(256) void softmax_rows_k(const float* __restrict__ att,
                                                      _Float16* __restrict__ P) {
  __shared__ float red[4];
  long row = blockIdx.x;
  int t = threadIdx.x, w = t >> 6;
  float4 x = ((const float4*)(att + row * 1024))[t];
  float m = fmaxf(fmaxf(x.x, x.y), fmaxf(x.z, x.w));
  m = wave_max(m);
  if ((t & 63) == 0) red[w] = m;
  __syncthreads();
  m = fmaxf(fmaxf(red[0], red[1]), fmaxf(red[2], red[3]));
  float e0 = expf(x.x - m), e1 = expf(x.y - m), e2 = expf(x.z - m), e3 = expf(x.w - m);
  float s = wave_sum(e0 + e1 + e2 + e3);
  __syncthreads();
  if ((t & 63) == 0) red[w] = s;
  __syncthreads();
  float inv = 1.0f / (red[0] + red[1] + red[2] + red[3]);
  f16x4 o;
  o[0] = (_Float16)(e0 * inv); o[1] = (_Float16)(e1 * inv);
  o[2] = (_Float16)(e2 * inv); o[3] = (_Float16)(e3 * inv);
  ((f16x4*)(P + row * 1024))[t] = o;
}

// ---------------- s = sigmoid(vv+hv+zz) -> z_new[:, :D]; u = s . Wu ----------------
__global__ __launch_bounds__(256) void s_u_k(const _Float16* __restrict__ Vv,
                                             const float* __restrict__ Hv,
                                             const _Float16* __restrict__ Zz,
                                             const float* __restrict__ Wu,
                                             float* __restrict__ zout,
                                             float* __restrict__ u) {
  __shared__ float red[4];
  long row = blockIdx.x;
  int t = threadIdx.x, w = t >> 6;
  f16x4 a = ((const f16x4*)(Vv + row * 1024))[t];
  float4 b = ((const float4*)(Hv + row * 1024))[t];
  f16x4 c = ((const f16x4*)(Zz + row * 1024))[t];
  float4 wu = ((const float4*)Wu)[t];
  float4 sv;
  sv.x = 1.0f / (1.0f + expf(-((float)a[0] + b.x + (float)c[0])));
  sv.y = 1.0f / (1.0f + expf(-((float)a[1] + b.y + (float)c[1])));
  sv.z = 1.0f / (1.0f + expf(-((float)a[2] + b.z + (float)c[2])));
  sv.w = 1.0f / (1.0f + expf(-((float)a[3] + b.w + (float)c[3])));
  ((float4*)(zout + row * 2048))[t] = sv;
  float part = sv.x * wu.x + sv.y * wu.y + sv.z * wu.z + sv.w * wu.w;
  part = wave_sum(part);
  if ((t & 63) == 0) red[w] = part;
  __syncthreads();
  if (t == 0) u[row] = red[0] + red[1] + red[2] + red[3];
}

// ---------------- per-batch softmax over u (masked) ----------------
__global__ __launch_bounds__(256) void u_softmax_k(const float* __restrict__ u,
                                                   const int* __restrict__ vmask,
                                                   float* __restrict__ p) {
  __shared__ float red[4];
  int b = blockIdx.x, t = threadIdx.x, w = t >> 6;
  float4 uv = ((const float4*)(u + b * 1024))[t];
  int4 mv = ((const int4*)(vmask + b * 1024))[t];
  float l0 = mv.x ? uv.x : -1e30f;
  float l1 = mv.y ? uv.y : -1e30f;
  float l2 = mv.z ? uv.z : -1e30f;
  float l3 = mv.w ? uv.w : -1e30f;
  float m = wave_max(fmaxf(fmaxf(l0, l1), fmaxf(l2, l3)));
  if ((t & 63) == 0) red[w] = m;
  __syncthreads();
  m = fmaxf(fmaxf(red[0], red[1]), fmaxf(red[2], red[3]));
  float e0 = expf(l0 - m), e1 = expf(l1 - m), e2 = expf(l2 - m), e3 = expf(l3 - m);
  float s = wave_sum(e0 + e1 + e2 + e3);
  __syncthreads();
  if ((t & 63) == 0) red[w] = s;
  __syncthreads();
  float inv = 1.0f / (red[0] + red[1] + red[2] + red[3]);
  float4 o = make_float4(e0 * inv, e1 * inv, e2 * inv, e3 * inv);
  ((float4*)(p + b * 1024))[t] = o;
}

// ---------------- f[b,d] = sum_j p[b,j] * v[b,j,d] (partials via atomics) ----------------
__global__ __launch_bounds__(256) void f_part_k(const float* __restrict__ p,
                                               const float* __restrict__ v,
                                               float* __restrict__ f) {
  int d = blockIdx.x * 256 + threadIdx.x;  // gridDim.x = 4
  int b = blockIdx.y;                      // 16
  int jc = blockIdx.z;                     // 8 chunks of 128
  const float* vb = v + ((long)b * NV + jc * 128) * DD + d;
  const float* pb = p + b * NV + jc * 128;
  float acc = 0.0f;
#pragma unroll 4
  for (int j = 0; j < 128; ++j) acc = fmaf(pb[j], vb[(long)j * DD], acc);
  atomicAdd(&f[b * DD + d], acc);
}

// ---------------- broadcast f into h_new and z_new[:, D:] ----------------
__global__ __launch_bounds__(256) void bcast_k(const float* __restrict__ f,
                                               float* __restrict__ hout,
                                               float* __restrict__ zout) {
  long idx = (long)blockIdx.x * 256 + threadIdx.x;  // float4 units
  int d4 = (int)(idx & 255);
  long bn = idx >> 8;
  int b = (int)(bn >> 10);
  float4 val = ((const float4*)f)[(b << 8) + d4];
  ((float4*)hout)[idx] = val;
  ((float4*)zout)[bn * 512 + 256 + d4] = val;
}

// ---------------- host ----------------
extern "C" void kernel_launch(void* const* d_in, const int* in_sizes, int n_in,
                              void* d_out, int out_size, void* d_ws, size_t ws_size,
                              hipStream_t stream) {
  const float* v = (const float*)d_in[0];
  const float* h = (const float*)d_in[1];
  const float* z = (const float*)d_in[2];
  const int* v_mask = (const int*)d_in[3];
  const int* h_mask = (const int*)d_in[4];
  const float* Wv_w = (const float*)d_in[5];
  const float* Wv_b = (const float*)d_in[6];
  const float* Wh_w = (const float*)d_in[7];
  const float* qv_w = (const float*)d_in[8];
  const float* qv_b = (const float*)d_in[9];
  const float* kh_w = (const float*)d_in[10];
  const float* Wz_w = (const float*)d_in[11];
  const float* Wu_w = (const float*)d_in[12];

  float* h_new = (float*)d_out;
  float* z_new = (float*)d_out + (long)BB * NV * DD;

  const size_t MB = 1u << 20;
  char* W = (char*)d_ws;
  // ---- workspace layout with aliasing (~401 MB) ----
  _Float16* vhi  = (_Float16*)(W + 0 * MB);     // alive to end
  _Float16* vlo  = (_Float16*)(W + 32 * MB);    // dead after Q -> P16
  _Float16* P16  = (_Float16*)(W + 32 * MB);
  _Float16* hhi  = (_Float16*)(W + 64 * MB);    // alive through Hht
  _Float16* hlo  = (_Float16*)(W + 96 * MB);    // dead after K -> Hht16
  _Float16* Hht16 = (_Float16*)(W + 96 * MB);
  _Float16* z16  = (_Float16*)(W + 128 * MB);   // 64 MB
  _Float16* qvhi = (_Float16*)(W + 192 * MB);
  _Float16* qvlo = (_Float16*)(W + 194 * MB);
  _Float16* khhi = (_Float16*)(W + 196 * MB);
  _Float16* khlo = (_Float16*)(W + 198 * MB);
  _Float16* Wv16 = (_Float16*)(W + 200 * MB);
  _Float16* Wh16 = (_Float16*)(W + 202 * MB);
  _Float16* Wz16 = (_Float16*)(W + 204 * MB);   // 4 MB
  _Float16* Qhi  = (_Float16*)(W + 208 * MB);   // dead after att -> Vv16
  _Float16* Vv16 = (_Float16*)(W + 208 * MB);
  _Float16* Qlo  = (_Float16*)(W + 240 * MB);   // dead after att -> Zz16
  _Float16* Zz16 = (_Float16*)(W + 240 * MB);
  _Float16* Khi  = (_Float16*)(W + 272 * MB);   // dead after att ┐
  _Float16* Klo  = (_Float16*)(W + 304 * MB);   //                ┘ -> Hv32 (64MB)
  float*    Hv32 = (float*)(W + 272 * MB);
  float*    att32 = (float*)(W + 336 * MB);     // 64 MB
  float*    u_buf = (float*)(W + 400 * MB);
  float*    p_buf = (float*)(W + 400 * MB + 65536);
  float*    f_buf = (float*)(W + 400 * MB + 2 * 65536);

  const long nVD = (long)BB * NV * DD;  // 16M
  const long s1M = (long)NV * DD;

  auto cast = [&](const float* src, _Float16* dst, long n) {
    long n4 = n / 4;
    cast_k<<<(int)((n4 + 255) / 256), 256, 0, stream>>>(src, dst, n4);
  };
  auto split = [&](const float* src, _Float16* hi, _Float16* lo, long n) {
    long n4 = n / 4;
    split_k<<<(int)((n4 + 255) / 256), 256, 0, stream>>>(src, hi, lo, n4);
  };

  // --- casts & splits ---
  split(v, vhi, vlo, nVD);
  split(h, hhi, hlo, nVD);
  cast(z, z16, nVD * 2);
  split(qv_w, qvhi, qvlo, (long)DD * DD);
  split(kh_w, khhi, khlo, (long)DD * DD);
  cast(Wv_w, Wv16, (long)DD * DD);
  cast(Wh_w, Wh16, (long)DD * DD);
  cast(Wz_w, Wz16, (long)DD * 2 * DD);

  // --- Q = v @ qv^T + b (split-precision, split output) ---
  gemm3_256_k<true><<<256, 512, 0, stream>>>(vhi, vlo, qvhi, qvlo,
      nullptr, Qhi, Qlo, qv_b, nullptr, DD, 1, 0, 0, 0);
  // --- K = h @ kh^T (split-precision, split output, h_mask folded) ---
  gemm3_256_k<true><<<256, 512, 0, stream>>>(hhi, hlo, khhi, khlo,
      nullptr, Khi, Klo, nullptr, h_mask, DD, 1, 0, 0, 0);
  // --- att[b] = Q[b] @ K[b]^T (split-precision, fp32 out) ---
  gemm3_256_k<false><<<256, 512, 0, stream>>>(Qhi, Qlo, Khi, Klo,
      att32, nullptr, nullptr, nullptr, nullptr, DD, BB, s1M, s1M, s1M);
  // --- P = softmax(att) rows (P16 over dead vlo) ---
  softmax_rows_k<<<BB * NV, 256, 0, stream>>>(att32, P16);
  // --- Hht[b][d,n] = Wh @ h[b]^T (over dead hlo) ---
  gemm256_nt_k<_Float16><<<256, 512, 0, stream>>>(Wh16, hhi, Hht16, nullptr, DD, BB, 0, s1M, s1M);
  // --- Vv = v @ Wv^T + b (over dead Qhi) ---
  gemm256_nt_k<_Float16><<<256, 512, 0, stream>>>(vhi, Wv16, Vv16, Wv_b, DD, 1, 0, 0, 0);
  // --- Zz = z @ Wz^T, K=2048 (over dead Qlo) ---
  gemm256_nt_k<_Float16><<<256, 512, 0, stream>>>(z16, Wz16, Zz16, nullptr, 2 * DD, 1, 0, 0, 0);
  // --- Hv[b] = P[b] @ Hht[b]^T, fp32 out (over dead Khi/Klo) ---
  gemm256_nt_k<float><<<256, 512, 0, stream>>>(P16, Hht16, Hv32, nullptr, NH, BB, s1M, s1M, s1M);
  // --- s, u ---
  s_u_k<<<BB * NV, 256, 0, stream>>>(Vv16, Hv32, Zz16, Wu_w, z_new, u_buf);
  // --- p = softmax(u) per batch ---
  u_softmax_k<<<BB, 256, 0, stream>>>(u_buf, v_mask, p_buf);
  // --- f = p @ v ---
  hipMemsetAsync(f_buf, 0, (long)BB * DD * 4, stream);
  f_part_k<<<dim3(4, BB, 8), 256, 0, stream>>>(p_buf, v, f_buf);
  // --- broadcast ---
  bcast_k<<<(int)(nVD / 4 / 256), 256, 0, stream>>>(f_buf, h_new, z_new);
}